// Round 7
// baseline (163.508 us; speedup 1.0000x reference)
//
#include <hip/hip_runtime.h>

#define NPOS 1024
#define BB   32
#define SS   1024
#define ALPHA_C 0.3f
#define CAP  128    // max source rows per hist row; Poisson(32), P(>128) ~ 0
#define PAD  1024   // ELL pad index -> zero slot in LDS row buffer
#define OCAP 1024   // per-batch overflow capacity (cannot be exceeded)
#define GROUP 4     // source rows staged/gathered per barrier
#define ROWSTRIDE (NPOS + 2)

// ---- K1a: bucket (b,p1) source-row indices by target row r = adds[b,p1] ----
__global__ __launch_bounds__(256) void build_rowlists(
    const int* __restrict__ adds, int* __restrict__ cnt, int* __restrict__ list) {
    const int i = blockIdx.x * 256 + threadIdx.x;   // [0, B*S)
    const int r = adds[i];
    const int slot = atomicAdd(&cnt[r], 1);
    if (slot < CAP) list[r * CAP + slot] = i;
}

// ---- K1b: per-batch ELL(W=4) column table + overflow COO ----
__global__ __launch_bounds__(1024) void build_colell(
    const int* __restrict__ adds, int* __restrict__ ell,
    int* __restrict__ ocnt, int* __restrict__ oent) {
    __shared__ int scnt[NPOS];
    __shared__ int so;
    const int b = blockIdx.x, t = threadIdx.x;
    const int c = adds[b * SS + t];
    ((int4*)ell)[b * NPOS + t] = make_int4(PAD, PAD, PAD, PAD);
    scnt[t] = 0;
    if (t == 0) so = 0;
    __syncthreads();
    const int slot = atomicAdd(&scnt[c], 1);
    if (slot < 4) {
        ell[(b * NPOS + c) * 4 + slot] = t;
    } else {
        const int o = atomicAdd(&so, 1);
        if (o < OCAP) oent[b * OCAP + o] = (c << 10) | t;        // pack (c,p2)
    }
    __syncthreads();
    if (t == 0) ocnt[b] = (so < OCAP) ? so : OCAP;
}

// ---- K2: block per hist row r; 512 threads own columns t and t+512.
// GROUP=4 rows staged per barrier (double-buffered half-groups); ELL gather
// with index loads pipelined one row ahead. No atomics. ----
__global__ __launch_bounds__(512, 6) void hist_rows_kernel(
    const float* __restrict__ a, const int* __restrict__ rowcnt,
    const int* __restrict__ rowlist, const int* __restrict__ ell,
    const int* __restrict__ ocnt, const int* __restrict__ oent,
    float* __restrict__ hist) {
    __shared__ float buf[2 * GROUP][ROWSTRIDE];   // [..][PAD] = 0.0f zero slot
    __shared__ int   lsrc[CAP];
    const int r = blockIdx.x, t = threadIdx.x;

    int n = rowcnt[r]; if (n > CAP) n = CAP;
    if (t < CAP && t < n) lsrc[t] = rowlist[r * CAP + t];
    if (t < 2 * GROUP) buf[t][PAD] = 0.f;
    __syncthreads();

    const int4* ell4 = (const int4*)ell;

    // stage group 0 into half 0
    #pragma unroll
    for (int g = 0; g < GROUP; ++g) {
        if (g < n) {
            const int src = lsrc[g];
            ((float2*)buf[g])[t] = ((const float2*)(a + (size_t)src * SS))[t];
        }
    }
    // prime index pipeline for k=0
    int4 e0 = make_int4(PAD, PAD, PAD, PAD), e1 = e0;
    if (n > 0) {
        const int bb0 = lsrc[0] >> 10;
        e0 = ell4[bb0 * NPOS + t];
        e1 = ell4[bb0 * NPOS + t + 512];
    }
    float acc0 = 0.f, acc1 = 0.f;

    for (int gi = 0; gi * GROUP < n; ++gi) {
        __syncthreads();   // group gi staged; prior gathers of other half done
        const int base = gi * GROUP;
        const int cur  = (gi & 1) * GROUP;
        const int nxt  = ((gi + 1) & 1) * GROUP;

        // stage next group into the other half (loads issue early)
        #pragma unroll
        for (int g = 0; g < GROUP; ++g) {
            const int k = base + GROUP + g;
            if (k < n) {
                const int src = lsrc[k];
                ((float2*)buf[nxt + g])[t] = ((const float2*)(a + (size_t)src * SS))[t];
            }
        }
        // gather current group
        #pragma unroll
        for (int g = 0; g < GROUP; ++g) {
            const int k = base + g;
            if (k >= n) break;
            int4 f0 = make_int4(PAD, PAD, PAD, PAD), f1 = f0;
            if (k + 1 < n) {                          // pipeline indices for k+1
                const int bbn = lsrc[k + 1] >> 10;
                f0 = ell4[bbn * NPOS + t];
                f1 = ell4[bbn * NPOS + t + 512];
            }
            const float* rb = buf[cur + g];
            acc0 += rb[e0.x] + rb[e0.y] + rb[e0.z] + rb[e0.w];
            acc1 += rb[e1.x] + rb[e1.y] + rb[e1.z] + rb[e1.w];
            const int bb = lsrc[k] >> 10;
            const int oc = ocnt[bb];                  // rare overflow entries
            const int* ob = oent + bb * OCAP;
            for (int j = 0; j < oc; ++j) {
                const int e = ob[j];
                const int c = e >> 10, p = e & 1023;
                if (c == t)            acc0 += rb[p];
                else if (c == t + 512) acc1 += rb[p];
            }
            e0 = f0; e1 = f1;
        }
    }
    hist[(size_t)r * NPOS + t]       = 1.f / (1.f + __expf(-acc0));
    hist[(size_t)r * NPOS + t + 512] = 1.f / (1.f + __expf(-acc1));
}

// ---- K3: out = s + 0.3 * score[pos[b,p1]*1024 + pos[b,p2]] ----
__global__ __launch_bounds__(256) void gather_kernel(
    const float* __restrict__ s, const int* __restrict__ pos,
    const float* __restrict__ score, float* __restrict__ out) {
    const int row = blockIdx.x;
    const int b   = row >> 10;
    const int*  posb = pos + b * SS;
    const int   base = posb[row & 1023] * NPOS;
    const size_t off = (size_t)row * SS;

    const int t = threadIdx.x;
    float4 v = ((const float4*)(s + off))[t];
    int4   c = ((const int4*)posb)[t];
    float4 o;
    o.x = v.x + ALPHA_C * score[base + c.x];
    o.y = v.y + ALPHA_C * score[base + c.y];
    o.z = v.z + ALPHA_C * score[base + c.z];
    o.w = v.w + ALPHA_C * score[base + c.w];
    ((float4*)(out + off))[t] = o;
}

extern "C" void kernel_launch(void* const* d_in, const int* in_sizes, int n_in,
                              void* d_out, int out_size, void* d_ws, size_t ws_size,
                              hipStream_t stream) {
    const float* s_arc = (const float*)d_in[0];
    const float* a_arc = (const float*)d_in[1];
    const int*   adds  = (const int*)d_in[2];
    const int*   pos   = (const int*)d_in[3];
    float* out  = (float*)d_out;

    // ws layout: [hist 4MB][cnt 4KB][list 512KB][ell 512KB][ocnt 128B][oent 128KB]
    float* hist = (float*)d_ws;
    int*   cnt  = (int*)((char*)d_ws + (size_t)NPOS * NPOS * sizeof(float));
    int*   list = cnt + NPOS;
    int*   ell  = list + NPOS * CAP;
    int*   ocnt = ell + BB * NPOS * 4;
    int*   oent = ocnt + BB;

    hipMemsetAsync(cnt, 0, NPOS * sizeof(int), stream);
    build_rowlists<<<(BB * SS) / 256, 256, 0, stream>>>(adds, cnt, list);
    build_colell<<<BB, 1024, 0, stream>>>(adds, ell, ocnt, oent);
    hist_rows_kernel<<<NPOS, 512, 0, stream>>>(a_arc, cnt, list, ell, ocnt, oent, hist);
    gather_kernel<<<BB * SS, 256, 0, stream>>>(s_arc, pos, hist, out);
}

// Round 8
// 161.276 us; speedup vs baseline: 1.0138x; 1.0138x over previous
//
#include <hip/hip_runtime.h>

#define NPOS 1024
#define BB   32
#define SS   1024
#define ALPHA_C 0.3f
#define CAP  128    // max source rows per hist row; Poisson(32), P(>128) ~ 0
#define PAD  1024   // ELL pad index -> zero slot in LDS row buffer
#define OCAP 1024   // per-batch overflow capacity (cannot be exceeded)
#define MAXO 64     // overflow entries/batch processed by fixup (E~4, P(>64)~0)

// ---- K1a: bucket (b,p1) source-row indices by target row r = adds[b,p1] ----
__global__ __launch_bounds__(256) void build_rowlists(
    const int* __restrict__ adds, int* __restrict__ cnt, int* __restrict__ list) {
    const int i = blockIdx.x * 256 + threadIdx.x;   // [0, B*S)
    const int r = adds[i];
    const int slot = atomicAdd(&cnt[r], 1);
    if (slot < CAP) list[r * CAP + slot] = i;
}

// ---- K1b: per-batch ELL(W=4) column table + overflow COO ----
__global__ __launch_bounds__(1024) void build_colell(
    const int* __restrict__ adds, int* __restrict__ ell,
    int* __restrict__ ocnt, int* __restrict__ oent) {
    __shared__ int scnt[NPOS];
    __shared__ int so;
    const int b = blockIdx.x, t = threadIdx.x;
    const int c = adds[b * SS + t];
    ((int4*)ell)[b * NPOS + t] = make_int4(PAD, PAD, PAD, PAD);
    scnt[t] = 0;
    if (t == 0) so = 0;
    __syncthreads();
    const int slot = atomicAdd(&scnt[c], 1);
    if (slot < 4) {
        ell[(b * NPOS + c) * 4 + slot] = t;
    } else {
        const int o = atomicAdd(&so, 1);
        if (o < OCAP) oent[b * OCAP + o] = (c << 10) | t;        // pack (c,p2)
    }
    __syncthreads();
    if (t == 0) ocnt[b] = (so < OCAP) ? so : OCAP;
}

// ---- K1c: overflow fixup — rare (~120 total) entries accumulated into the
// zeroed hist via global atomics, BEFORE hist_rows adds its sums on top. ----
__global__ __launch_bounds__(256) void overflow_fixup(
    const float* __restrict__ a, const int* __restrict__ adds,
    const int* __restrict__ ocnt, const int* __restrict__ oent,
    float* __restrict__ hist) {
    const int b  = blockIdx.x;              // batch
    const int ei = blockIdx.y;              // overflow entry index
    if (ei >= ocnt[b]) return;
    const int e  = oent[b * OCAP + ei];
    const int c  = e >> 10, p2 = e & 1023;
    const int p1 = blockIdx.z * 256 + threadIdx.x;
    const int r  = adds[b * SS + p1];
    const float v = a[((size_t)(b * SS + p1)) * SS + p2];
    atomicAdd(&hist[(size_t)r * NPOS + c], v);
}

// ---- K2: block per hist row r; 512 threads own columns t and t+512.
// Double-buffered LDS row staging; ELL gather (8 independent ds_reads/thread),
// indices prefetched one row ahead. No atomics, NO overflow loop. ----
__global__ __launch_bounds__(512) void hist_rows_kernel(
    const float* __restrict__ a, const int* __restrict__ rowcnt,
    const int* __restrict__ rowlist, const int* __restrict__ ell,
    float* __restrict__ hist) {
    __shared__ float buf[2][NPOS + 2];   // [..][PAD] = 0.0f zero slot
    __shared__ int   lsrc[CAP];
    const int r = blockIdx.x, t = threadIdx.x;

    int n = rowcnt[r]; if (n > CAP) n = CAP;
    if (t < CAP && t < n) lsrc[t] = rowlist[r * CAP + t];
    if (t == 0) { buf[0][PAD] = 0.f; buf[1][PAD] = 0.f; }
    __syncthreads();

    const int4* ell4 = (const int4*)ell;
    float acc0 = 0.f, acc1 = 0.f;
    int4 e0 = make_int4(PAD, PAD, PAD, PAD), e1 = e0;

    if (n > 0) {
        const int src0 = lsrc[0];
        const int bb0  = src0 >> 10;
        ((float2*)buf[0])[t] = ((const float2*)(a + (size_t)src0 * SS))[t];
        e0 = ell4[bb0 * NPOS + t];
        e1 = ell4[bb0 * NPOS + t + 512];
    }
    for (int k = 0; k < n; ++k) {
        __syncthreads();  // buf[k&1] staged; prior reads of buf[(k+1)&1] done
        int4 f0 = make_int4(PAD, PAD, PAD, PAD), f1 = f0;
        if (k + 1 < n) {
            const int srcn = lsrc[k + 1];
            const int bbn  = srcn >> 10;
            ((float2*)buf[(k + 1) & 1])[t] = ((const float2*)(a + (size_t)srcn * SS))[t];
            f0 = ell4[bbn * NPOS + t];
            f1 = ell4[bbn * NPOS + t + 512];
        }
        const float* rb = buf[k & 1];
        acc0 += rb[e0.x] + rb[e0.y] + rb[e0.z] + rb[e0.w];
        acc1 += rb[e1.x] + rb[e1.y] + rb[e1.z] + rb[e1.w];
        e0 = f0; e1 = f1;
    }
    const size_t o0 = (size_t)r * NPOS + t;
    const float base0 = hist[o0], base1 = hist[o0 + 512];   // fixup contributions
    hist[o0]       = 1.f / (1.f + __expf(-(base0 + acc0)));
    hist[o0 + 512] = 1.f / (1.f + __expf(-(base1 + acc1)));
}

// ---- K3: out = s + 0.3 * score[pos[b,p1]*1024 + pos[b,p2]] ----
__global__ __launch_bounds__(256) void gather_kernel(
    const float* __restrict__ s, const int* __restrict__ pos,
    const float* __restrict__ score, float* __restrict__ out) {
    const int row = blockIdx.x;
    const int b   = row >> 10;
    const int*  posb = pos + b * SS;
    const int   base = posb[row & 1023] * NPOS;
    const size_t off = (size_t)row * SS;

    const int t = threadIdx.x;
    float4 v = ((const float4*)(s + off))[t];
    int4   c = ((const int4*)posb)[t];
    float4 o;
    o.x = v.x + ALPHA_C * score[base + c.x];
    o.y = v.y + ALPHA_C * score[base + c.y];
    o.z = v.z + ALPHA_C * score[base + c.z];
    o.w = v.w + ALPHA_C * score[base + c.w];
    ((float4*)(out + off))[t] = o;
}

extern "C" void kernel_launch(void* const* d_in, const int* in_sizes, int n_in,
                              void* d_out, int out_size, void* d_ws, size_t ws_size,
                              hipStream_t stream) {
    const float* s_arc = (const float*)d_in[0];
    const float* a_arc = (const float*)d_in[1];
    const int*   adds  = (const int*)d_in[2];
    const int*   pos   = (const int*)d_in[3];
    float* out  = (float*)d_out;

    // ws layout: [hist 4MB][cnt 4KB][list 512KB][ell 512KB][ocnt 128B][oent 128KB]
    float* hist = (float*)d_ws;
    int*   cnt  = (int*)((char*)d_ws + (size_t)NPOS * NPOS * sizeof(float));
    int*   list = cnt + NPOS;
    int*   ell  = list + NPOS * CAP;
    int*   ocnt = ell + BB * NPOS * 4;
    int*   oent = ocnt + BB;

    hipMemsetAsync(cnt, 0, NPOS * sizeof(int), stream);
    hipMemsetAsync(hist, 0, (size_t)NPOS * NPOS * sizeof(float), stream);
    build_rowlists<<<(BB * SS) / 256, 256, 0, stream>>>(adds, cnt, list);
    build_colell<<<BB, 1024, 0, stream>>>(adds, ell, ocnt, oent);
    overflow_fixup<<<dim3(BB, MAXO, SS / 256), 256, 0, stream>>>(a_arc, adds, ocnt, oent, hist);
    hist_rows_kernel<<<NPOS, 512, 0, stream>>>(a_arc, cnt, list, ell, hist);
    gather_kernel<<<BB * SS, 256, 0, stream>>>(s_arc, pos, hist, out);
}

// Round 9
// 141.820 us; speedup vs baseline: 1.1529x; 1.1372x over previous
//
#include <hip/hip_runtime.h>

#define NPOS 1024
#define BB   32
#define SS   1024
#define ALPHA_C 0.3f
#define CAP  128    // max source rows per hist row; Poisson(32), P(>128) ~ 0
#define PAD  1024   // ELL pad index -> zero slot in LDS row buffer
#define OCAP 1024   // per-batch overflow capacity (cannot be exceeded)
#define MAXO 16     // overflow entries/batch processed by fixup (E~4, P(>16)~1e-6)
#define PADPAIR 0x04000400u   // two packed 16-bit PADs

// ---- K1a: bucket (b,p1) source-row indices by target row r = adds[b,p1] ----
__global__ __launch_bounds__(256) void build_rowlists(
    const int* __restrict__ adds, int* __restrict__ cnt, int* __restrict__ list) {
    const int i = blockIdx.x * 256 + threadIdx.x;   // [0, B*S)
    const int r = adds[i];
    const int slot = atomicAdd(&cnt[r], 1);
    if (slot < CAP) list[r * CAP + slot] = i;
}

// ---- K1b: per-batch 16-bit ELL(W=4) + overflow COO ----
// ushort ell16, laid out [b][pair=c&511][half=c>>9][slot 0..3]:
// one uint4 per thread t covers columns t and t+512 -> coalesced 16B loads in K2.
__global__ __launch_bounds__(1024) void build_colell(
    const int* __restrict__ adds, ushort* __restrict__ ell16,
    int* __restrict__ ocnt, int* __restrict__ oent) {
    __shared__ int scnt[NPOS];
    __shared__ int so;
    const int b = blockIdx.x, t = threadIdx.x;
    const int c = adds[b * SS + t];
    ((uint2*)ell16)[b * 1024 + t] = make_uint2(PADPAIR, PADPAIR);  // init 8B each
    scnt[t] = 0;
    if (t == 0) so = 0;
    __syncthreads();
    const int slot = atomicAdd(&scnt[c], 1);
    if (slot < 4) {
        ell16[(((size_t)b * 512 + (c & 511)) * 2 + (c >> 9)) * 4 + slot] = (ushort)t;
    } else {
        const int o = atomicAdd(&so, 1);
        if (o < OCAP) oent[b * OCAP + o] = (c << 10) | t;        // pack (c,p2)
    }
    __syncthreads();
    if (t == 0) ocnt[b] = (so < OCAP) ? so : OCAP;
}

// ---- K1c: overflow fixup — rare (~120 total) entries accumulated into the
// zeroed hist via global atomics, BEFORE hist_rows adds its sums on top. ----
__global__ __launch_bounds__(256) void overflow_fixup(
    const float* __restrict__ a, const int* __restrict__ adds,
    const int* __restrict__ ocnt, const int* __restrict__ oent,
    float* __restrict__ hist) {
    const int b  = blockIdx.x;              // batch
    const int ei = blockIdx.y;              // overflow entry index
    if (ei >= ocnt[b]) return;
    const int e  = oent[b * OCAP + ei];
    const int c  = e >> 10, p2 = e & 1023;
    const int p1 = blockIdx.z * 256 + threadIdx.x;
    const int r  = adds[b * SS + p1];
    const float v = a[((size_t)(b * SS + p1)) * SS + p2];
    atomicAdd(&hist[(size_t)r * NPOS + c], v);
}

// ---- K2: block per hist row r; 512 threads own columns t and t+512.
// Register double-staging (issue row k+2's load at iter k, ds_write at k+1),
// 16-bit ELL indices (one uint4/thread), index prefetch one row ahead. ----
__global__ __launch_bounds__(512) void hist_rows_kernel(
    const float* __restrict__ a, const int* __restrict__ rowcnt,
    const int* __restrict__ rowlist, const ushort* __restrict__ ell16,
    float* __restrict__ hist) {
    __shared__ float buf[2][NPOS + 2];   // [..][PAD] = 0.0f zero slot
    __shared__ int   lsrc[CAP];
    const int r = blockIdx.x, t = threadIdx.x;

    int n = rowcnt[r]; if (n > CAP) n = CAP;
    if (t < CAP && t < n) lsrc[t] = rowlist[r * CAP + t];
    if (t == 0) { buf[0][PAD] = 0.f; buf[1][PAD] = 0.f; }
    __syncthreads();

    const uint4* ellv = (const uint4*)ell16;   // [b*512 + t] = cols (t, t+512)
    float acc0 = 0.f, acc1 = 0.f;
    uint4  E = make_uint4(PADPAIR, PADPAIR, PADPAIR, PADPAIR);
    float2 Rb = make_float2(0.f, 0.f);

    if (n > 0) {
        const int s0 = lsrc[0];
        const float2 R0 = ((const float2*)(a + (size_t)s0 * SS))[t];
        E = ellv[(size_t)(s0 >> 10) * 512 + t];
        ((float2*)buf[0])[t] = R0;
    }
    if (n > 1) {
        const int s1 = lsrc[1];
        Rb = ((const float2*)(a + (size_t)s1 * SS))[t];   // in flight across barrier
    }
    __syncthreads();

    for (int k = 0; k < n; ++k) {
        // prefetch indices for row k+1 (L2-hot, one iteration of latency)
        uint4 F = make_uint4(PADPAIR, PADPAIR, PADPAIR, PADPAIR);
        if (k + 1 < n) F = ellv[(size_t)(lsrc[k + 1] >> 10) * 512 + t];

        // gather row k from buf[k&1]
        const float* rb = buf[k & 1];
        acc0 += rb[E.x & 0xffffu]; acc0 += rb[E.x >> 16];
        acc0 += rb[E.y & 0xffffu]; acc0 += rb[E.y >> 16];
        acc1 += rb[E.z & 0xffffu]; acc1 += rb[E.z >> 16];
        acc1 += rb[E.w & 0xffffu]; acc1 += rb[E.w >> 16];

        // write staged row k+1 (arrived during this iteration's gather),
        // then issue the load for row k+2 into the freed registers
        if (k + 1 < n) ((float2*)buf[(k + 1) & 1])[t] = Rb;
        if (k + 2 < n) Rb = ((const float2*)(a + (size_t)lsrc[k + 2] * SS))[t];

        E = F;
        __syncthreads();
    }

    const size_t o0 = (size_t)r * NPOS + t;
    const float base0 = hist[o0], base1 = hist[o0 + 512];   // fixup contributions
    hist[o0]       = 1.f / (1.f + __expf(-(base0 + acc0)));
    hist[o0 + 512] = 1.f / (1.f + __expf(-(base1 + acc1)));
}

// ---- K3: out = s + 0.3 * score[pos[b,p1]*1024 + pos[b,p2]] ----
__global__ __launch_bounds__(256) void gather_kernel(
    const float* __restrict__ s, const int* __restrict__ pos,
    const float* __restrict__ score, float* __restrict__ out) {
    const int row = blockIdx.x;
    const int b   = row >> 10;
    const int*  posb = pos + b * SS;
    const int   base = posb[row & 1023] * NPOS;
    const size_t off = (size_t)row * SS;

    const int t = threadIdx.x;
    float4 v = ((const float4*)(s + off))[t];
    int4   c = ((const int4*)posb)[t];
    float4 o;
    o.x = v.x + ALPHA_C * score[base + c.x];
    o.y = v.y + ALPHA_C * score[base + c.y];
    o.z = v.z + ALPHA_C * score[base + c.z];
    o.w = v.w + ALPHA_C * score[base + c.w];
    ((float4*)(out + off))[t] = o;
}

extern "C" void kernel_launch(void* const* d_in, const int* in_sizes, int n_in,
                              void* d_out, int out_size, void* d_ws, size_t ws_size,
                              hipStream_t stream) {
    const float* s_arc = (const float*)d_in[0];
    const float* a_arc = (const float*)d_in[1];
    const int*   adds  = (const int*)d_in[2];
    const int*   pos   = (const int*)d_in[3];
    float* out  = (float*)d_out;

    // ws layout: [hist 4MB][cnt 4KB][list 512KB][ell16 256KB][ocnt 128B][oent 128KB]
    float*  hist  = (float*)d_ws;
    int*    cnt   = (int*)((char*)d_ws + (size_t)NPOS * NPOS * sizeof(float));
    int*    list  = cnt + NPOS;
    ushort* ell16 = (ushort*)(list + NPOS * CAP);
    int*    ocnt  = (int*)(ell16 + (size_t)BB * NPOS * 4);
    int*    oent  = ocnt + BB;

    // hist and cnt are contiguous: one memset covers both
    hipMemsetAsync(hist, 0, (size_t)NPOS * NPOS * sizeof(float) + NPOS * sizeof(int), stream);
    build_rowlists<<<(BB * SS) / 256, 256, 0, stream>>>(adds, cnt, list);
    build_colell<<<BB, 1024, 0, stream>>>(adds, ell16, ocnt, oent);
    overflow_fixup<<<dim3(BB, MAXO, SS / 256), 256, 0, stream>>>(a_arc, adds, ocnt, oent, hist);
    hist_rows_kernel<<<NPOS, 512, 0, stream>>>(a_arc, cnt, list, ell16, hist);
    gather_kernel<<<BB * SS, 256, 0, stream>>>(s_arc, pos, hist, out);
}

// Round 10
// 141.189 us; speedup vs baseline: 1.1581x; 1.0045x over previous
//
#include <hip/hip_runtime.h>

#define NPOS 1024
#define BB   32
#define SS   1024
#define ALPHA_C 0.3f
#define CAP  128    // max source rows per hist row; Poisson(32), P(>128) ~ 0
#define PAD  1024   // ELL pad index -> zero slot in LDS row buffer
#define OCAP 1024   // per-batch overflow capacity (cannot be exceeded)
#define MAXO 16     // overflow entries/batch processed by fixup (E~4, P(>16)~1e-6)
#define PADPAIR 0x04000400u   // two packed 16-bit PADs

// ---- K0: fast zero-fill of hist (4MB) + cnt (4KB); rocclr's fillBuffer is ~75us ----
__global__ __launch_bounds__(256) void zero_fill(float4* __restrict__ p) {
    p[blockIdx.x * 256 + threadIdx.x] = make_float4(0.f, 0.f, 0.f, 0.f);
}

// ---- K1a: bucket (b,p1) source-row indices by target row r = adds[b,p1] ----
__global__ __launch_bounds__(256) void build_rowlists(
    const int* __restrict__ adds, int* __restrict__ cnt, int* __restrict__ list) {
    const int i = blockIdx.x * 256 + threadIdx.x;   // [0, B*S)
    const int r = adds[i];
    const int slot = atomicAdd(&cnt[r], 1);
    if (slot < CAP) list[r * CAP + slot] = i;
}

// ---- K1b: per-batch 16-bit ELL(W=4) + overflow COO ----
// ushort ell16, laid out [b][pair=c&511][half=c>>9][slot 0..3]:
// one uint4 per thread t covers columns t and t+512 -> coalesced 16B loads in K2.
__global__ __launch_bounds__(1024) void build_colell(
    const int* __restrict__ adds, ushort* __restrict__ ell16,
    int* __restrict__ ocnt, int* __restrict__ oent) {
    __shared__ int scnt[NPOS];
    __shared__ int so;
    const int b = blockIdx.x, t = threadIdx.x;
    const int c = adds[b * SS + t];
    ((uint2*)ell16)[b * 1024 + t] = make_uint2(PADPAIR, PADPAIR);  // init 8B each
    scnt[t] = 0;
    if (t == 0) so = 0;
    __syncthreads();
    const int slot = atomicAdd(&scnt[c], 1);
    if (slot < 4) {
        ell16[(((size_t)b * 512 + (c & 511)) * 2 + (c >> 9)) * 4 + slot] = (ushort)t;
    } else {
        const int o = atomicAdd(&so, 1);
        if (o < OCAP) oent[b * OCAP + o] = (c << 10) | t;        // pack (c,p2)
    }
    __syncthreads();
    if (t == 0) ocnt[b] = (so < OCAP) ? so : OCAP;
}

// ---- K1c: overflow fixup — rare (~120 total) entries accumulated into the
// zeroed hist via global atomics, BEFORE hist_rows adds its sums on top. ----
__global__ __launch_bounds__(256) void overflow_fixup(
    const float* __restrict__ a, const int* __restrict__ adds,
    const int* __restrict__ ocnt, const int* __restrict__ oent,
    float* __restrict__ hist) {
    const int b  = blockIdx.x;              // batch
    const int ei = blockIdx.y;              // overflow entry index
    if (ei >= ocnt[b]) return;
    const int e  = oent[b * OCAP + ei];
    const int c  = e >> 10, p2 = e & 1023;
    const int p1 = blockIdx.z * 256 + threadIdx.x;
    const int r  = adds[b * SS + p1];
    const float v = a[((size_t)(b * SS + p1)) * SS + p2];
    atomicAdd(&hist[(size_t)r * NPOS + c], v);
}

// ---- K2: block per hist row r; 512 threads own columns t and t+512.
// Register double-staging (issue row k+2's load at iter k, ds_write at k+1),
// 16-bit ELL indices (one uint4/thread), index prefetch one row ahead. ----
__global__ __launch_bounds__(512) void hist_rows_kernel(
    const float* __restrict__ a, const int* __restrict__ rowcnt,
    const int* __restrict__ rowlist, const ushort* __restrict__ ell16,
    float* __restrict__ hist) {
    __shared__ float buf[2][NPOS + 2];   // [..][PAD] = 0.0f zero slot
    __shared__ int   lsrc[CAP];
    const int r = blockIdx.x, t = threadIdx.x;

    int n = rowcnt[r]; if (n > CAP) n = CAP;
    if (t < CAP && t < n) lsrc[t] = rowlist[r * CAP + t];
    if (t == 0) { buf[0][PAD] = 0.f; buf[1][PAD] = 0.f; }
    __syncthreads();

    const uint4* ellv = (const uint4*)ell16;   // [b*512 + t] = cols (t, t+512)
    float acc0 = 0.f, acc1 = 0.f;
    uint4  E = make_uint4(PADPAIR, PADPAIR, PADPAIR, PADPAIR);
    float2 Rb = make_float2(0.f, 0.f);

    if (n > 0) {
        const int s0 = lsrc[0];
        const float2 R0 = ((const float2*)(a + (size_t)s0 * SS))[t];
        E = ellv[(size_t)(s0 >> 10) * 512 + t];
        ((float2*)buf[0])[t] = R0;
    }
    if (n > 1) {
        const int s1 = lsrc[1];
        Rb = ((const float2*)(a + (size_t)s1 * SS))[t];   // in flight across barrier
    }
    __syncthreads();

    for (int k = 0; k < n; ++k) {
        // prefetch indices for row k+1 (L2-hot, one iteration of latency)
        uint4 F = make_uint4(PADPAIR, PADPAIR, PADPAIR, PADPAIR);
        if (k + 1 < n) F = ellv[(size_t)(lsrc[k + 1] >> 10) * 512 + t];

        // gather row k from buf[k&1]
        const float* rb = buf[k & 1];
        acc0 += rb[E.x & 0xffffu]; acc0 += rb[E.x >> 16];
        acc0 += rb[E.y & 0xffffu]; acc0 += rb[E.y >> 16];
        acc1 += rb[E.z & 0xffffu]; acc1 += rb[E.z >> 16];
        acc1 += rb[E.w & 0xffffu]; acc1 += rb[E.w >> 16];

        // write staged row k+1 (arrived during this iteration's gather),
        // then issue the load for row k+2 into the freed registers
        if (k + 1 < n) ((float2*)buf[(k + 1) & 1])[t] = Rb;
        if (k + 2 < n) Rb = ((const float2*)(a + (size_t)lsrc[k + 2] * SS))[t];

        E = F;
        __syncthreads();
    }

    const size_t o0 = (size_t)r * NPOS + t;
    const float base0 = hist[o0], base1 = hist[o0 + 512];   // fixup contributions
    hist[o0]       = 1.f / (1.f + __expf(-(base0 + acc0)));
    hist[o0 + 512] = 1.f / (1.f + __expf(-(base1 + acc1)));
}

// ---- K3: out = s + 0.3 * score[pos[b,p1]*1024 + pos[b,p2]] ----
__global__ __launch_bounds__(256) void gather_kernel(
    const float* __restrict__ s, const int* __restrict__ pos,
    const float* __restrict__ score, float* __restrict__ out) {
    const int row = blockIdx.x;
    const int b   = row >> 10;
    const int*  posb = pos + b * SS;
    const int   base = posb[row & 1023] * NPOS;
    const size_t off = (size_t)row * SS;

    const int t = threadIdx.x;
    float4 v = ((const float4*)(s + off))[t];
    int4   c = ((const int4*)posb)[t];
    float4 o;
    o.x = v.x + ALPHA_C * score[base + c.x];
    o.y = v.y + ALPHA_C * score[base + c.y];
    o.z = v.z + ALPHA_C * score[base + c.z];
    o.w = v.w + ALPHA_C * score[base + c.w];
    ((float4*)(out + off))[t] = o;
}

extern "C" void kernel_launch(void* const* d_in, const int* in_sizes, int n_in,
                              void* d_out, int out_size, void* d_ws, size_t ws_size,
                              hipStream_t stream) {
    const float* s_arc = (const float*)d_in[0];
    const float* a_arc = (const float*)d_in[1];
    const int*   adds  = (const int*)d_in[2];
    const int*   pos   = (const int*)d_in[3];
    float* out  = (float*)d_out;

    // ws layout: [hist 4MB][cnt 4KB][list 512KB][ell16 256KB][ocnt 128B][oent 128KB]
    float*  hist  = (float*)d_ws;
    int*    cnt   = (int*)((char*)d_ws + (size_t)NPOS * NPOS * sizeof(float));
    int*    list  = cnt + NPOS;
    ushort* ell16 = (ushort*)(list + NPOS * CAP);
    int*    ocnt  = (int*)(ell16 + (size_t)BB * NPOS * 4);
    int*    oent  = ocnt + BB;

    // hist (4MB) + cnt (4KB) are contiguous: 1025 blocks x 256 thr x 16B exactly
    zero_fill<<<1025, 256, 0, stream>>>((float4*)hist);
    build_rowlists<<<(BB * SS) / 256, 256, 0, stream>>>(adds, cnt, list);
    build_colell<<<BB, 1024, 0, stream>>>(adds, ell16, ocnt, oent);
    overflow_fixup<<<dim3(BB, MAXO, SS / 256), 256, 0, stream>>>(a_arc, adds, ocnt, oent, hist);
    hist_rows_kernel<<<NPOS, 512, 0, stream>>>(a_arc, cnt, list, ell16, hist);
    gather_kernel<<<BB * SS, 256, 0, stream>>>(s_arc, pos, hist, out);
}

// Round 11
// 141.162 us; speedup vs baseline: 1.1583x; 1.0002x over previous
//
#include <hip/hip_runtime.h>

#define NPOS 1024
#define BB   32
#define SS   1024
#define ALPHA_C 0.3f
#define CAP  128    // max source rows per hist row; Poisson(32), P(>128) ~ 0
#define PAD  1024   // ELL pad index -> zero slot in LDS row buffer
#define OCAP 1024   // per-batch overflow capacity (cannot be exceeded)
#define MAXO 16     // overflow entries/batch processed by fixup (E~4, P(>16)~1e-6)
#define PADPAIR 0x04000400u   // two packed 16-bit PADs

// ---- K0: fast zero-fill of hist (4MB) + cnt (4KB); rocclr's fillBuffer is slow ----
__global__ __launch_bounds__(256) void zero_fill(float4* __restrict__ p) {
    p[blockIdx.x * 256 + threadIdx.x] = make_float4(0.f, 0.f, 0.f, 0.f);
}

// ---- K1a: bucket (b,p1) source-row indices by target row r = adds[b,p1] ----
__global__ __launch_bounds__(256) void build_rowlists(
    const int* __restrict__ adds, int* __restrict__ cnt, int* __restrict__ list) {
    const int i = blockIdx.x * 256 + threadIdx.x;   // [0, B*S)
    const int r = adds[i];
    const int slot = atomicAdd(&cnt[r], 1);
    if (slot < CAP) list[r * CAP + slot] = i;
}

// ---- K1b: per-batch 16-bit ELL(W=4) + overflow COO ----
// ushort ell16, laid out [b][pair=c&511][half=c>>9][slot 0..3]:
// one uint4 per thread t covers columns t and t+512 -> coalesced 16B loads in K2.
__global__ __launch_bounds__(1024) void build_colell(
    const int* __restrict__ adds, ushort* __restrict__ ell16,
    int* __restrict__ ocnt, int* __restrict__ oent) {
    __shared__ int scnt[NPOS];
    __shared__ int so;
    const int b = blockIdx.x, t = threadIdx.x;
    const int c = adds[b * SS + t];
    ((uint2*)ell16)[b * 1024 + t] = make_uint2(PADPAIR, PADPAIR);  // init 8B each
    scnt[t] = 0;
    if (t == 0) so = 0;
    __syncthreads();
    const int slot = atomicAdd(&scnt[c], 1);
    if (slot < 4) {
        ell16[(((size_t)b * 512 + (c & 511)) * 2 + (c >> 9)) * 4 + slot] = (ushort)t;
    } else {
        const int o = atomicAdd(&so, 1);
        if (o < OCAP) oent[b * OCAP + o] = (c << 10) | t;        // pack (c,p2)
    }
    __syncthreads();
    if (t == 0) ocnt[b] = (so < OCAP) ? so : OCAP;
}

// ---- K1c: overflow fixup — rare (~120 total) entries accumulated into the
// zeroed hist via global atomics, BEFORE hist_rows adds its sums on top. ----
__global__ __launch_bounds__(256) void overflow_fixup(
    const float* __restrict__ a, const int* __restrict__ adds,
    const int* __restrict__ ocnt, const int* __restrict__ oent,
    float* __restrict__ hist) {
    const int b  = blockIdx.x;              // batch
    const int ei = blockIdx.y;              // overflow entry index
    if (ei >= ocnt[b]) return;
    const int e  = oent[b * OCAP + ei];
    const int c  = e >> 10, p2 = e & 1023;
    const int p1 = blockIdx.z * 256 + threadIdx.x;
    const int r  = adds[b * SS + p1];
    const float v = a[((size_t)(b * SS + p1)) * SS + p2];
    atomicAdd(&hist[(size_t)r * NPOS + c], v);
}

// ---- K2: block per hist row r; 512 threads own columns t and t+512.
// Register double-staging with COUNTED-vmcnt barrier: lgkmcnt(0)+s_barrier only,
// so the k+2 stage load and k+1 ELL prefetch stay in flight across the barrier
// (__syncthreads would drain vmcnt(0) and re-expose L3 latency every iter). ----
__global__ __launch_bounds__(512) void hist_rows_kernel(
    const float* __restrict__ a, const int* __restrict__ rowcnt,
    const int* __restrict__ rowlist, const ushort* __restrict__ ell16,
    float* __restrict__ hist) {
    __shared__ float buf[2][NPOS + 2];   // [..][PAD] = 0.0f zero slot
    __shared__ int   lsrc[CAP];
    const int r = blockIdx.x, t = threadIdx.x;

    int n = rowcnt[r]; if (n > CAP) n = CAP;
    if (t < CAP && t < n) lsrc[t] = rowlist[r * CAP + t];
    if (t == 0) { buf[0][PAD] = 0.f; buf[1][PAD] = 0.f; }
    __syncthreads();

    const uint4* ellv = (const uint4*)ell16;   // [b*512 + t] = cols (t, t+512)
    float acc0 = 0.f, acc1 = 0.f;
    uint4  E = make_uint4(PADPAIR, PADPAIR, PADPAIR, PADPAIR);
    float2 Rb = make_float2(0.f, 0.f);

    if (n > 0) {
        const int s0 = lsrc[0];
        const float2 R0 = ((const float2*)(a + (size_t)s0 * SS))[t];
        E = ellv[(size_t)(s0 >> 10) * 512 + t];
        ((float2*)buf[0])[t] = R0;
    }
    if (n > 1) {
        const int s1 = lsrc[1];
        Rb = ((const float2*)(a + (size_t)s1 * SS))[t];   // in flight across barrier
    }
    __syncthreads();

    for (int k = 0; k < n; ++k) {
        // prefetch indices for row k+1 (L2-hot; consumed next iteration)
        uint4 F = make_uint4(PADPAIR, PADPAIR, PADPAIR, PADPAIR);
        if (k + 1 < n) F = ellv[(size_t)(lsrc[k + 1] >> 10) * 512 + t];

        // gather row k from buf[k&1] (pure LDS + VALU; no vmem waits)
        const float* rb = buf[k & 1];
        acc0 += rb[E.x & 0xffffu]; acc0 += rb[E.x >> 16];
        acc0 += rb[E.y & 0xffffu]; acc0 += rb[E.y >> 16];
        acc1 += rb[E.z & 0xffffu]; acc1 += rb[E.z >> 16];
        acc1 += rb[E.w & 0xffffu]; acc1 += rb[E.w >> 16];
        __builtin_amdgcn_sched_barrier(0);   // keep gather ahead of the vmcnt wait below

        // write staged row k+1 (compiler inserts exact counted vmcnt wait for Rb),
        // then issue the load for row k+2 into the freed registers
        if (k + 1 < n) ((float2*)buf[(k + 1) & 1])[t] = Rb;
        if (k + 2 < n) Rb = ((const float2*)(a + (size_t)lsrc[k + 2] * SS))[t];

        E = F;
        // lgkm drain (ds_write visibility) but NO vmcnt drain: Rb/F span the barrier
        asm volatile("s_waitcnt lgkmcnt(0)" ::: "memory");
        __builtin_amdgcn_s_barrier();
    }

    const size_t o0 = (size_t)r * NPOS + t;
    const float base0 = hist[o0], base1 = hist[o0 + 512];   // fixup contributions
    hist[o0]       = 1.f / (1.f + __expf(-(base0 + acc0)));
    hist[o0 + 512] = 1.f / (1.f + __expf(-(base1 + acc1)));
}

// ---- K3: out = s + 0.3 * score[pos[b,p1]*1024 + pos[b,p2]] ----
__global__ __launch_bounds__(256) void gather_kernel(
    const float* __restrict__ s, const int* __restrict__ pos,
    const float* __restrict__ score, float* __restrict__ out) {
    const int row = blockIdx.x;
    const int b   = row >> 10;
    const int*  posb = pos + b * SS;
    const int   base = posb[row & 1023] * NPOS;
    const size_t off = (size_t)row * SS;

    const int t = threadIdx.x;
    float4 v = ((const float4*)(s + off))[t];
    int4   c = ((const int4*)posb)[t];
    float4 o;
    o.x = v.x + ALPHA_C * score[base + c.x];
    o.y = v.y + ALPHA_C * score[base + c.y];
    o.z = v.z + ALPHA_C * score[base + c.z];
    o.w = v.w + ALPHA_C * score[base + c.w];
    ((float4*)(out + off))[t] = o;
}

extern "C" void kernel_launch(void* const* d_in, const int* in_sizes, int n_in,
                              void* d_out, int out_size, void* d_ws, size_t ws_size,
                              hipStream_t stream) {
    const float* s_arc = (const float*)d_in[0];
    const float* a_arc = (const float*)d_in[1];
    const int*   adds  = (const int*)d_in[2];
    const int*   pos   = (const int*)d_in[3];
    float* out  = (float*)d_out;

    // ws layout: [hist 4MB][cnt 4KB][list 512KB][ell16 256KB][ocnt 128B][oent 128KB]
    float*  hist  = (float*)d_ws;
    int*    cnt   = (int*)((char*)d_ws + (size_t)NPOS * NPOS * sizeof(float));
    int*    list  = cnt + NPOS;
    ushort* ell16 = (ushort*)(list + NPOS * CAP);
    int*    ocnt  = (int*)(ell16 + (size_t)BB * NPOS * 4);
    int*    oent  = ocnt + BB;

    // hist (4MB) + cnt (4KB) are contiguous: 1025 blocks x 256 thr x 16B exactly
    zero_fill<<<1025, 256, 0, stream>>>((float4*)hist);
    build_rowlists<<<(BB * SS) / 256, 256, 0, stream>>>(adds, cnt, list);
    build_colell<<<BB, 1024, 0, stream>>>(adds, ell16, ocnt, oent);
    overflow_fixup<<<dim3(BB, MAXO, SS / 256), 256, 0, stream>>>(a_arc, adds, ocnt, oent, hist);
    hist_rows_kernel<<<NPOS, 512, 0, stream>>>(a_arc, cnt, list, ell16, hist);
    gather_kernel<<<BB * SS, 256, 0, stream>>>(s_arc, pos, hist, out);
}